// Round 1
// baseline (144.327 us; speedup 1.0000x reference)
//
#include <hip/hip_runtime.h>
#include <math.h>

#define NPTS   2048
#define BDIM   256
#define PPT    (NPTS / BDIM)   // 8 points per thread
#define NACC   27
#define NITERS 10
#define DAMPF  1e-8f

__launch_bounds__(BDIM, 1)
__global__ void lie_gn_kernel(const float* __restrict__ src4,
                              const float* __restrict__ trg4,
                              const float* __restrict__ wts,
                              const float* __restrict__ Tinit,
                              const float* __restrict__ icov,
                              const float* __restrict__ Tsv,
                              float* __restrict__ out)
{
    const int b    = blockIdx.x;
    const int tid  = threadIdx.x;
    const int lane = tid & 63;
    const int wid  = tid >> 6;

    __shared__ float shT[12];                 // R (row-major 9) + t (3)
    __shared__ float red[BDIM / 64][NACC];    // per-wave partials

    const float* srcb = src4 + (size_t)b * 4 * NPTS;
    const float* trgb = trg4 + (size_t)b * 4 * NPTS;
    const float* wb   = wts  + (size_t)b * NPTS;
    const float* cb   = icov + (size_t)b * NPTS * 9;

    // ---- per-point data, register-resident for all iterations ----
    float sx[PPT], sy[PPT], sz[PPT];
    float gx[PPT], gy[PPT], gz[PPT];
    float W0[PPT], W1[PPT], W2[PPT], W3[PPT], W4[PPT], W5[PPT];

    #pragma unroll
    for (int k = 0; k < PPT; ++k) {
        int n = tid + k * BDIM;
        sx[k] = srcb[n];
        sy[k] = srcb[NPTS + n];
        sz[k] = srcb[2 * NPTS + n];
        gx[k] = trgb[n];
        gy[k] = trgb[NPTS + n];
        gz[k] = trgb[2 * NPTS + n];
        float w  = wb[n];
        float w2 = 2.0f * w * w;
        const float* c = cb + (size_t)n * 9;
        // W = 2*w^2 * inv_cov (symmetric; read lower triangle like chol does)
        W0[k] = w2 * c[0];   // xx
        W1[k] = w2 * c[3];   // xy
        W2[k] = w2 * c[6];   // xz
        W3[k] = w2 * c[4];   // yy
        W4[k] = w2 * c[7];   // yz
        W5[k] = w2 * c[8];   // zz
    }

    if (tid < 9)                 shT[tid] = Tinit[b * 16 + (tid / 3) * 4 + (tid % 3)];
    if (tid >= 9 && tid < 12)    shT[tid] = Tinit[b * 16 + (tid - 9) * 4 + 3];
    __syncthreads();

    for (int it = 0; it < NITERS; ++it) {
        const float R00 = shT[0], R01 = shT[1], R02 = shT[2];
        const float R10 = shT[3], R11 = shT[4], R12 = shT[5];
        const float R20 = shT[6], R21 = shT[7], R22 = shT[8];
        const float tx  = shT[9], ty  = shT[10], tz = shT[11];

        float acc[NACC];
        #pragma unroll
        for (int k = 0; k < NACC; ++k) acc[k] = 0.0f;

        #pragma unroll
        for (int k = 0; k < PPT; ++k) {
            // p~ = R*s  (NOT including t — the Jacobian uses hat(R*s))
            float px = R00 * sx[k] + R01 * sy[k] + R02 * sz[k];
            float py = R10 * sx[k] + R11 * sy[k] + R12 * sz[k];
            float pz = R20 * sx[k] + R21 * sy[k] + R22 * sz[k];
            // residual e = trg - (R*s + t)
            float ex = gx[k] - px - tx;
            float ey = gy[k] - py - ty;
            float ez = gz[k] - pz - tz;
            float w0 = W0[k], w1 = W1[k], w2 = W2[k];
            float w3 = W3[k], w4 = W4[k], w5 = W5[k];
            // u = W*e
            float ux = w0 * ex + w1 * ey + w2 * ez;
            float uy = w1 * ex + w3 * ey + w4 * ez;
            float uz = w2 * ex + w4 * ey + w5 * ez;
            // M = W * hat(p~)
            float M00 = w1 * pz - w2 * py;
            float M01 = w2 * px - w0 * pz;
            float M02 = w0 * py - w1 * px;
            float M10 = w3 * pz - w4 * py;
            float M11 = w4 * px - w1 * pz;
            float M12 = w1 * py - w3 * px;
            float M20 = w4 * pz - w5 * py;
            float M21 = w5 * px - w2 * pz;
            float M22 = w2 * py - w4 * px;

            acc[0] += w0;  acc[1] += w1;  acc[2] += w2;
            acc[3] += w3;  acc[4] += w4;  acc[5] += w5;
            acc[6]  += M00; acc[7]  += M01; acc[8]  += M02;
            acc[9]  += M10; acc[10] += M11; acc[11] += M12;
            acc[12] += M20; acc[13] += M21; acc[14] += M22;
            // N = hat(p~) * M  (symmetric), unique entries
            acc[15] += py * M20 - pz * M10;   // N00
            acc[16] += py * M21 - pz * M11;   // N01
            acc[17] += py * M22 - pz * M12;   // N02
            acc[18] += pz * M01 - px * M21;   // N11
            acc[19] += pz * M02 - px * M22;   // N12
            acc[20] += px * M12 - py * M02;   // N22
            acc[21] += ux; acc[22] += uy; acc[23] += uz;
            acc[24] += py * uz - pz * uy;     // p~ x u
            acc[25] += pz * ux - px * uz;
            acc[26] += px * uy - py * ux;
        }

        // wave (64-lane) shuffle reduction
        #pragma unroll
        for (int k = 0; k < NACC; ++k) {
            float v = acc[k];
            v += __shfl_down(v, 32, 64);
            v += __shfl_down(v, 16, 64);
            v += __shfl_down(v, 8, 64);
            v += __shfl_down(v, 4, 64);
            v += __shfl_down(v, 2, 64);
            v += __shfl_down(v, 1, 64);
            acc[k] = v;
        }
        if (lane == 0) {
            #pragma unroll
            for (int k = 0; k < NACC; ++k) red[wid][k] = acc[k];
        }
        __syncthreads();

        if (tid == 0) {
            float s[NACC];
            #pragma unroll
            for (int k = 0; k < NACC; ++k)
                s[k] = red[0][k] + red[1][k] + red[2][k] + red[3][k];

            // Hhat = [[SW, -SM], [-SM^T, -SN]] + damp*I ; rhs = (Su, Sq)
            float Hm[6][6];
            Hm[0][0] = s[0]; Hm[0][1] = s[1]; Hm[0][2] = s[2];
            Hm[1][1] = s[3]; Hm[1][2] = s[4]; Hm[2][2] = s[5];
            Hm[0][3] = -s[6];  Hm[0][4] = -s[7];  Hm[0][5] = -s[8];
            Hm[1][3] = -s[9];  Hm[1][4] = -s[10]; Hm[1][5] = -s[11];
            Hm[2][3] = -s[12]; Hm[2][4] = -s[13]; Hm[2][5] = -s[14];
            Hm[3][3] = -s[15]; Hm[3][4] = -s[16]; Hm[3][5] = -s[17];
            Hm[4][4] = -s[18]; Hm[4][5] = -s[19]; Hm[5][5] = -s[20];
            #pragma unroll
            for (int i = 0; i < 6; ++i) {
                Hm[i][i] += DAMPF;
                #pragma unroll
                for (int j = 0; j < 6; ++j)
                    if (j < i) Hm[i][j] = Hm[j][i];
            }
            float rhs[6] = { s[21], s[22], s[23], s[24], s[25], s[26] };

            // Cholesky H = L L^T (SPD)
            float L[6][6];
            #pragma unroll
            for (int i = 0; i < 6; ++i) {
                #pragma unroll
                for (int j = 0; j < 6; ++j) {
                    if (j > i) continue;
                    float sum = Hm[i][j];
                    #pragma unroll
                    for (int k2 = 0; k2 < 6; ++k2)
                        if (k2 < j) sum -= L[i][k2] * L[j][k2];
                    if (i == j) L[i][i] = sqrtf(sum);
                    else        L[i][j] = sum / L[j][j];
                }
            }
            float z[6];
            #pragma unroll
            for (int i = 0; i < 6; ++i) {
                float sum = rhs[i];
                #pragma unroll
                for (int k2 = 0; k2 < 6; ++k2)
                    if (k2 < i) sum -= L[i][k2] * z[k2];
                z[i] = sum / L[i][i];
            }
            float y[6];
            #pragma unroll
            for (int i = 5; i >= 0; --i) {
                float sum = z[i];
                #pragma unroll
                for (int k2 = 0; k2 < 6; ++k2)
                    if (k2 > i) sum -= L[k2][i] * y[k2];
                y[i] = sum / L[i][i];
            }

            // dx = diag(R,R)^T * y
            float drx = R00 * y[0] + R10 * y[1] + R20 * y[2];
            float dry = R01 * y[0] + R11 * y[1] + R21 * y[2];
            float drz = R02 * y[0] + R12 * y[1] + R22 * y[2];
            float dpx = R00 * y[3] + R10 * y[4] + R20 * y[5];
            float dpy = R01 * y[3] + R11 * y[4] + R21 * y[5];
            float dpz = R02 * y[3] + R12 * y[4] + R22 * y[5];

            // se3_exp(dx)
            float th2 = dpx * dpx + dpy * dpy + dpz * dpz;
            bool  sm  = th2 < 1e-12f;
            float th2s = sm ? 1.0f : th2;
            float th   = sqrtf(th2s);
            float sth  = sinf(th), cth = cosf(th);
            float Ae = sm ? 1.0f : sth / th;
            float Be = sm ? 0.5f : (1.0f - cth) / th2s;
            float Ce = sm ? (1.0f / 6.0f) : (th - sth) / (th2s * th);
            // K2 = pp^T - th2*I (exact identity)
            float Rd00 = 1.0f + Be * (dpx * dpx - th2);
            float Rd01 = -Ae * dpz + Be * dpx * dpy;
            float Rd02 =  Ae * dpy + Be * dpx * dpz;
            float Rd10 =  Ae * dpz + Be * dpx * dpy;
            float Rd11 = 1.0f + Be * (dpy * dpy - th2);
            float Rd12 = -Ae * dpx + Be * dpy * dpz;
            float Rd20 = -Ae * dpy + Be * dpx * dpz;
            float Rd21 =  Ae * dpx + Be * dpy * dpz;
            float Rd22 = 1.0f + Be * (dpz * dpz - th2);
            float V00 = 1.0f + Ce * (dpx * dpx - th2);
            float V01 = -Be * dpz + Ce * dpx * dpy;
            float V02 =  Be * dpy + Ce * dpx * dpz;
            float V10 =  Be * dpz + Ce * dpx * dpy;
            float V11 = 1.0f + Ce * (dpy * dpy - th2);
            float V12 = -Be * dpx + Ce * dpy * dpz;
            float V20 = -Be * dpy + Ce * dpx * dpz;
            float V21 =  Be * dpx + Ce * dpy * dpz;
            float V22 = 1.0f + Ce * (dpz * dpz - th2);
            float tdx = V00 * drx + V01 * dry + V02 * drz;
            float tdy = V10 * drx + V11 * dry + V12 * drz;
            float tdz = V20 * drx + V21 * dry + V22 * drz;

            // T <- T * exp(dx)
            float nR00 = R00 * Rd00 + R01 * Rd10 + R02 * Rd20;
            float nR01 = R00 * Rd01 + R01 * Rd11 + R02 * Rd21;
            float nR02 = R00 * Rd02 + R01 * Rd12 + R02 * Rd22;
            float nR10 = R10 * Rd00 + R11 * Rd10 + R12 * Rd20;
            float nR11 = R10 * Rd01 + R11 * Rd11 + R12 * Rd21;
            float nR12 = R10 * Rd02 + R11 * Rd12 + R12 * Rd22;
            float nR20 = R20 * Rd00 + R21 * Rd10 + R22 * Rd20;
            float nR21 = R20 * Rd01 + R21 * Rd11 + R22 * Rd21;
            float nR22 = R20 * Rd02 + R21 * Rd12 + R22 * Rd22;
            float ntx  = R00 * tdx + R01 * tdy + R02 * tdz + tx;
            float nty  = R10 * tdx + R11 * tdy + R12 * tdz + ty;
            float ntz  = R20 * tdx + R21 * tdy + R22 * tdz + tz;

            shT[0] = nR00; shT[1] = nR01; shT[2] = nR02;
            shT[3] = nR10; shT[4] = nR11; shT[5] = nR12;
            shT[6] = nR20; shT[7] = nR21; shT[8] = nR22;
            shT[9] = ntx;  shT[10] = nty; shT[11] = ntz;
        }
        __syncthreads();
    }

    // epilogue: Out = inv(Tsv) * T * Tsv
    if (tid == 0) {
        float R00 = shT[0], R01 = shT[1], R02 = shT[2];
        float R10 = shT[3], R11 = shT[4], R12 = shT[5];
        float R20 = shT[6], R21 = shT[7], R22 = shT[8];
        float tx  = shT[9], ty  = shT[10], tz = shT[11];

        float Rv00 = Tsv[0], Rv01 = Tsv[1], Rv02 = Tsv[2],  tvx = Tsv[3];
        float Rv10 = Tsv[4], Rv11 = Tsv[5], Rv12 = Tsv[6],  tvy = Tsv[7];
        float Rv20 = Tsv[8], Rv21 = Tsv[9], Rv22 = Tsv[10], tvz = Tsv[11];

        // P = T * Tsv
        float P00 = R00 * Rv00 + R01 * Rv10 + R02 * Rv20;
        float P01 = R00 * Rv01 + R01 * Rv11 + R02 * Rv21;
        float P02 = R00 * Rv02 + R01 * Rv12 + R02 * Rv22;
        float P10 = R10 * Rv00 + R11 * Rv10 + R12 * Rv20;
        float P11 = R10 * Rv01 + R11 * Rv11 + R12 * Rv21;
        float P12 = R10 * Rv02 + R11 * Rv12 + R12 * Rv22;
        float P20 = R20 * Rv00 + R21 * Rv10 + R22 * Rv20;
        float P21 = R20 * Rv01 + R21 * Rv11 + R22 * Rv21;
        float P22 = R20 * Rv02 + R21 * Rv12 + R22 * Rv22;
        float Ptx = R00 * tvx + R01 * tvy + R02 * tvz + tx;
        float Pty = R10 * tvx + R11 * tvy + R12 * tvz + ty;
        float Ptz = R20 * tvx + R21 * tvy + R22 * tvz + tz;

        // Out = [Rv^T * P | Rv^T * (Pt - tv)]
        float ex = Ptx - tvx, ey = Pty - tvy, ez = Ptz - tvz;
        float* o = out + (size_t)b * 16;
        o[0]  = Rv00 * P00 + Rv10 * P10 + Rv20 * P20;
        o[1]  = Rv00 * P01 + Rv10 * P11 + Rv20 * P21;
        o[2]  = Rv00 * P02 + Rv10 * P12 + Rv20 * P22;
        o[3]  = Rv00 * ex  + Rv10 * ey  + Rv20 * ez;
        o[4]  = Rv01 * P00 + Rv11 * P10 + Rv21 * P20;
        o[5]  = Rv01 * P01 + Rv11 * P11 + Rv21 * P21;
        o[6]  = Rv01 * P02 + Rv11 * P12 + Rv21 * P22;
        o[7]  = Rv01 * ex  + Rv11 * ey  + Rv21 * ez;
        o[8]  = Rv02 * P00 + Rv12 * P10 + Rv22 * P20;
        o[9]  = Rv02 * P01 + Rv12 * P11 + Rv22 * P21;
        o[10] = Rv02 * P02 + Rv12 * P12 + Rv22 * P22;
        o[11] = Rv02 * ex  + Rv12 * ey  + Rv22 * ez;
        o[12] = 0.0f; o[13] = 0.0f; o[14] = 0.0f; o[15] = 1.0f;
    }
}

extern "C" void kernel_launch(void* const* d_in, const int* in_sizes, int n_in,
                              void* d_out, int out_size, void* d_ws, size_t ws_size,
                              hipStream_t stream)
{
    const float* src4  = (const float*)d_in[0];
    const float* trg4  = (const float*)d_in[1];
    const float* wts   = (const float*)d_in[2];
    const float* Tinit = (const float*)d_in[3];
    const float* icov  = (const float*)d_in[4];
    const float* Tsv   = (const float*)d_in[5];

    const int B = in_sizes[3] / 16;   // T_trg_src_init is (B,4,4)

    hipLaunchKernelGGL(lie_gn_kernel, dim3(B), dim3(BDIM), 0, stream,
                       src4, trg4, wts, Tinit, icov, Tsv, (float*)d_out);
}

// Round 2
// 112.530 us; speedup vs baseline: 1.2826x; 1.2826x over previous
//
#include <hip/hip_runtime.h>
#include <math.h>

#define NPTS   2048
#define BD1    256
#define PPT    (NPTS / BD1)   // 8 points per thread in phase 1
#define NMOM   72
#define NITERS 10
#define DAMPF  1e-8f

// ---------------------------------------------------------------------------
// Phase 1: per-batch iteration-independent moments (72 floats per batch).
// Layout per batch b (stored transposed: mom[k*B + b] for coalesced phase-2
// reads):
//   0..5   : SW[ij]            = sum W_ij                (sym idx 00,01,02,11,12,22)
//   6..23  : A1[ij][c]         = sum W_ij * s_c          (6+ij*3+c)
//   24..59 : A2[ij][cd]        = sum W_ij * s_c*s_d      (24+ij*6+cd, cd sym idx)
//   60..62 : b0[i]             = sum (W g)_i
//   63..71 : B1[c][i]          = sum s_c * (W g)_i       (63+c*3+i)
// ---------------------------------------------------------------------------
__launch_bounds__(BD1, 1)
__global__ void moments_kernel(const float* __restrict__ src4,
                               const float* __restrict__ trg4,
                               const float* __restrict__ wts,
                               const float* __restrict__ icov,
                               float* __restrict__ mom, int B)
{
    const int b   = blockIdx.x;
    const int tid = threadIdx.x;

    const float* srcb = src4 + (size_t)b * 4 * NPTS;
    const float* trgb = trg4 + (size_t)b * 4 * NPTS;
    const float* wb   = wts  + (size_t)b * NPTS;
    const float* cb   = icov + (size_t)b * NPTS * 9;

    float acc[NMOM];
    #pragma unroll
    for (int k = 0; k < NMOM; ++k) acc[k] = 0.0f;

    #pragma unroll
    for (int kk = 0; kk < PPT; ++kk) {
        int n = tid + kk * BD1;
        float sx = srcb[n], sy = srcb[NPTS + n], sz = srcb[2 * NPTS + n];
        float gx = trgb[n], gy = trgb[NPTS + n], gz = trgb[2 * NPTS + n];
        float w  = wb[n];
        const float* c = cb + (size_t)n * 9;
        float w2 = 2.0f * w * w;
        float W[6];
        W[0] = w2 * c[0];   // xx
        W[1] = w2 * c[3];   // xy (lower tri, as chol reads)
        W[2] = w2 * c[6];   // xz
        W[3] = w2 * c[4];   // yy
        W[4] = w2 * c[7];   // yz
        W[5] = w2 * c[8];   // zz

        float hx = W[0] * gx + W[1] * gy + W[2] * gz;
        float hy = W[1] * gx + W[3] * gy + W[4] * gz;
        float hz = W[2] * gx + W[4] * gy + W[5] * gz;

        float sv[3] = { sx, sy, sz };
        float hv[3] = { hx, hy, hz };
        float ss[6] = { sx*sx, sx*sy, sx*sz, sy*sy, sy*sz, sz*sz };

        #pragma unroll
        for (int ij = 0; ij < 6; ++ij) {
            acc[ij] += W[ij];
            #pragma unroll
            for (int c2 = 0; c2 < 3; ++c2) acc[6 + ij * 3 + c2] += W[ij] * sv[c2];
            #pragma unroll
            for (int cd = 0; cd < 6; ++cd) acc[24 + ij * 6 + cd] += W[ij] * ss[cd];
        }
        acc[60] += hx; acc[61] += hy; acc[62] += hz;
        #pragma unroll
        for (int c2 = 0; c2 < 3; ++c2)
            #pragma unroll
            for (int i = 0; i < 3; ++i) acc[63 + c2 * 3 + i] += sv[c2] * hv[i];
    }

    // Block reduction via LDS transpose (two halves of 36 to stay under the
    // static LDS cap). Row pad +1 -> conflict-light.
    __shared__ float lds[36][BD1 + 1];
    #pragma unroll
    for (int h = 0; h < 2; ++h) {
        if (h) __syncthreads();
        #pragma unroll
        for (int k = 0; k < 36; ++k) lds[k][tid] = acc[h * 36 + k];
        __syncthreads();
        if (tid < 36) {
            const float* row = lds[tid];
            float s0 = 0.f, s1 = 0.f, s2 = 0.f, s3 = 0.f;
            #pragma unroll 8
            for (int j = 0; j < BD1; j += 4) {
                s0 += row[j]; s1 += row[j + 1]; s2 += row[j + 2]; s3 += row[j + 3];
            }
            mom[(h * 36 + tid) * B + b] = (s0 + s1) + (s2 + s3);
        }
    }
}

// ---------------------------------------------------------------------------
// Phase 2: one thread per batch. 10 GN iterations assembled from moments.
// ---------------------------------------------------------------------------
__launch_bounds__(64, 1)
__global__ void solve_kernel(const float* __restrict__ mom,
                             const float* __restrict__ Tinit,
                             const float* __restrict__ Tsv,
                             float* __restrict__ out, int B)
{
    const int b = blockIdx.x * 64 + threadIdx.x;
    if (b >= B) return;

    float m[NMOM];
    #pragma unroll
    for (int k = 0; k < NMOM; ++k) m[k] = mom[k * B + b];

    float Rm[3][3], tv[3];
    #pragma unroll
    for (int i = 0; i < 3; ++i) {
        #pragma unroll
        for (int j = 0; j < 3; ++j) Rm[i][j] = Tinit[b * 16 + i * 4 + j];
        tv[i] = Tinit[b * 16 + i * 4 + 3];
    }

    const int SY[3][3] = { {0,1,2}, {1,3,4}, {2,4,5} };

    for (int it = 0; it < NITERS; ++it) {
        // C1[ij][a] = sum W_ij * p_a  (p = R s)
        float C1[6][3];
        #pragma unroll
        for (int ij = 0; ij < 6; ++ij) {
            float a0 = m[6 + ij * 3 + 0], a1 = m[6 + ij * 3 + 1], a2 = m[6 + ij * 3 + 2];
            #pragma unroll
            for (int a = 0; a < 3; ++a)
                C1[ij][a] = Rm[a][0] * a0 + Rm[a][1] * a1 + Rm[a][2] * a2;
        }
        // SM = sum W hat(p);  SWp = sum W p
        float SM[3][3], SWp[3];
        #pragma unroll
        for (int i = 0; i < 3; ++i) {
            SM[i][0] = C1[SY[i][1]][2] - C1[SY[i][2]][1];
            SM[i][1] = C1[SY[i][2]][0] - C1[SY[i][0]][2];
            SM[i][2] = C1[SY[i][0]][1] - C1[SY[i][1]][0];
            SWp[i]   = C1[SY[i][0]][0] + C1[SY[i][1]][1] + C1[SY[i][2]][2];
        }
        // P2[ab][ij] = sum p_a p_b W_ij = (R A2[ij] R^T)_{ab}
        float P2[6][6];
        #pragma unroll
        for (int ij = 0; ij < 6; ++ij) {
            float S00 = m[24 + ij * 6 + 0], S01 = m[24 + ij * 6 + 1], S02 = m[24 + ij * 6 + 2];
            float S11 = m[24 + ij * 6 + 3], S12 = m[24 + ij * 6 + 4], S22 = m[24 + ij * 6 + 5];
            float U[3][3];
            #pragma unroll
            for (int a = 0; a < 3; ++a) {
                U[a][0] = Rm[a][0] * S00 + Rm[a][1] * S01 + Rm[a][2] * S02;
                U[a][1] = Rm[a][0] * S01 + Rm[a][1] * S11 + Rm[a][2] * S12;
                U[a][2] = Rm[a][0] * S02 + Rm[a][1] * S12 + Rm[a][2] * S22;
            }
            P2[0][ij] = U[0][0]*Rm[0][0] + U[0][1]*Rm[0][1] + U[0][2]*Rm[0][2];
            P2[1][ij] = U[0][0]*Rm[1][0] + U[0][1]*Rm[1][1] + U[0][2]*Rm[1][2];
            P2[2][ij] = U[0][0]*Rm[2][0] + U[0][1]*Rm[2][1] + U[0][2]*Rm[2][2];
            P2[3][ij] = U[1][0]*Rm[1][0] + U[1][1]*Rm[1][1] + U[1][2]*Rm[1][2];
            P2[4][ij] = U[1][0]*Rm[2][0] + U[1][1]*Rm[2][1] + U[1][2]*Rm[2][2];
            P2[5][ij] = U[2][0]*Rm[2][0] + U[2][1]*Rm[2][1] + U[2][2]*Rm[2][2];
        }
        // SN = sum hat(p) W hat(p), unique entries
        float SN00 = -P2[5][3] + 2.f * P2[4][4] - P2[3][5];
        float SN01 = -P2[2][4] + P2[5][1] + P2[1][5] - P2[4][2];
        float SN02 = -P2[4][1] + P2[2][3] + P2[3][2] - P2[1][4];
        float SN11 =  2.f * P2[2][2] - P2[5][0] - P2[0][5];
        float SN12 =  P2[4][0] - P2[2][1] - P2[1][2] + P2[0][4];
        float SN22 = -P2[3][0] + 2.f * P2[1][1] - P2[0][3];

        // Su = sum W e = b0 - SWp - SW*t
        float SWt0 = m[0]*tv[0] + m[1]*tv[1] + m[2]*tv[2];
        float SWt1 = m[1]*tv[0] + m[3]*tv[1] + m[4]*tv[2];
        float SWt2 = m[2]*tv[0] + m[4]*tv[1] + m[5]*tv[2];
        float Su[3] = { m[60] - SWp[0] - SWt0,
                        m[61] - SWp[1] - SWt1,
                        m[62] - SWp[2] - SWt2 };

        // Sq = sum p x u = sum p x h - sum p x (W p) + SM^T t
        float G[3][3];
        #pragma unroll
        for (int a = 0; a < 3; ++a)
            #pragma unroll
            for (int bb = 0; bb < 3; ++bb)
                G[a][bb] = Rm[a][0]*m[63 + 0 + bb] + Rm[a][1]*m[63 + 3 + bb] + Rm[a][2]*m[63 + 6 + bb];
        float ch[3] = { G[1][2] - G[2][1], G[2][0] - G[0][2], G[0][1] - G[1][0] };
        float pw[3];
        pw[0] = P2[1][2] + P2[3][4] + P2[4][5] - P2[2][1] - P2[4][3] - P2[5][4];
        pw[1] = P2[2][0] + P2[4][1] + P2[5][2] - P2[0][2] - P2[1][4] - P2[2][5];
        pw[2] = P2[0][1] + P2[1][3] + P2[2][4] - P2[1][0] - P2[3][1] - P2[4][2];
        float Sq[3];
        #pragma unroll
        for (int i = 0; i < 3; ++i)
            Sq[i] = ch[i] - pw[i] + SM[0][i]*tv[0] + SM[1][i]*tv[1] + SM[2][i]*tv[2];

        // H (hat frame) and rhs
        float Hm[6][6];
        Hm[0][0] = m[0]; Hm[0][1] = m[1]; Hm[0][2] = m[2];
        Hm[1][1] = m[3]; Hm[1][2] = m[4]; Hm[2][2] = m[5];
        #pragma unroll
        for (int i = 0; i < 3; ++i) {
            Hm[i][3] = -SM[i][0]; Hm[i][4] = -SM[i][1]; Hm[i][5] = -SM[i][2];
        }
        Hm[3][3] = -SN00; Hm[3][4] = -SN01; Hm[3][5] = -SN02;
        Hm[4][4] = -SN11; Hm[4][5] = -SN12; Hm[5][5] = -SN22;
        #pragma unroll
        for (int i = 0; i < 6; ++i) {
            Hm[i][i] += DAMPF;
            #pragma unroll
            for (int j = 0; j < 6; ++j)
                if (j < i) Hm[i][j] = Hm[j][i];
        }
        float rhs[6] = { Su[0], Su[1], Su[2], Sq[0], Sq[1], Sq[2] };

        // Cholesky solve
        float L[6][6];
        #pragma unroll
        for (int i = 0; i < 6; ++i) {
            #pragma unroll
            for (int j = 0; j < 6; ++j) {
                if (j > i) continue;
                float sum = Hm[i][j];
                #pragma unroll
                for (int k2 = 0; k2 < 6; ++k2)
                    if (k2 < j) sum -= L[i][k2] * L[j][k2];
                if (i == j) L[i][i] = sqrtf(sum);
                else        L[i][j] = sum / L[j][j];
            }
        }
        float z[6];
        #pragma unroll
        for (int i = 0; i < 6; ++i) {
            float sum = rhs[i];
            #pragma unroll
            for (int k2 = 0; k2 < 6; ++k2)
                if (k2 < i) sum -= L[i][k2] * z[k2];
            z[i] = sum / L[i][i];
        }
        float y[6];
        #pragma unroll
        for (int i = 5; i >= 0; --i) {
            float sum = z[i];
            #pragma unroll
            for (int k2 = 0; k2 < 6; ++k2)
                if (k2 > i) sum -= L[k2][i] * y[k2];
            y[i] = sum / L[i][i];
        }

        // dx = blockdiag(R,R)^T y
        float drx = Rm[0][0]*y[0] + Rm[1][0]*y[1] + Rm[2][0]*y[2];
        float dry = Rm[0][1]*y[0] + Rm[1][1]*y[1] + Rm[2][1]*y[2];
        float drz = Rm[0][2]*y[0] + Rm[1][2]*y[1] + Rm[2][2]*y[2];
        float dpx = Rm[0][0]*y[3] + Rm[1][0]*y[4] + Rm[2][0]*y[5];
        float dpy = Rm[0][1]*y[3] + Rm[1][1]*y[4] + Rm[2][1]*y[5];
        float dpz = Rm[0][2]*y[3] + Rm[1][2]*y[4] + Rm[2][2]*y[5];

        // se3_exp(dx)
        float th2  = dpx*dpx + dpy*dpy + dpz*dpz;
        bool  sm   = th2 < 1e-12f;
        float th2s = sm ? 1.0f : th2;
        float th   = sqrtf(th2s);
        float sth  = sinf(th), cth = cosf(th);
        float Ae = sm ? 1.0f : sth / th;
        float Be = sm ? 0.5f : (1.0f - cth) / th2s;
        float Ce = sm ? (1.0f / 6.0f) : (th - sth) / (th2s * th);
        float Rd00 = 1.0f + Be * (dpx*dpx - th2);
        float Rd01 = -Ae * dpz + Be * dpx * dpy;
        float Rd02 =  Ae * dpy + Be * dpx * dpz;
        float Rd10 =  Ae * dpz + Be * dpx * dpy;
        float Rd11 = 1.0f + Be * (dpy*dpy - th2);
        float Rd12 = -Ae * dpx + Be * dpy * dpz;
        float Rd20 = -Ae * dpy + Be * dpx * dpz;
        float Rd21 =  Ae * dpx + Be * dpy * dpz;
        float Rd22 = 1.0f + Be * (dpz*dpz - th2);
        float V00 = 1.0f + Ce * (dpx*dpx - th2);
        float V01 = -Be * dpz + Ce * dpx * dpy;
        float V02 =  Be * dpy + Ce * dpx * dpz;
        float V10 =  Be * dpz + Ce * dpx * dpy;
        float V11 = 1.0f + Ce * (dpy*dpy - th2);
        float V12 = -Be * dpx + Ce * dpy * dpz;
        float V20 = -Be * dpy + Ce * dpx * dpz;
        float V21 =  Be * dpx + Ce * dpy * dpz;
        float V22 = 1.0f + Ce * (dpz*dpz - th2);
        float tdx = V00 * drx + V01 * dry + V02 * drz;
        float tdy = V10 * drx + V11 * dry + V12 * drz;
        float tdz = V20 * drx + V21 * dry + V22 * drz;

        // T <- T * exp(dx)
        float nR[3][3];
        nR[0][0] = Rm[0][0]*Rd00 + Rm[0][1]*Rd10 + Rm[0][2]*Rd20;
        nR[0][1] = Rm[0][0]*Rd01 + Rm[0][1]*Rd11 + Rm[0][2]*Rd21;
        nR[0][2] = Rm[0][0]*Rd02 + Rm[0][1]*Rd12 + Rm[0][2]*Rd22;
        nR[1][0] = Rm[1][0]*Rd00 + Rm[1][1]*Rd10 + Rm[1][2]*Rd20;
        nR[1][1] = Rm[1][0]*Rd01 + Rm[1][1]*Rd11 + Rm[1][2]*Rd21;
        nR[1][2] = Rm[1][0]*Rd02 + Rm[1][1]*Rd12 + Rm[1][2]*Rd22;
        nR[2][0] = Rm[2][0]*Rd00 + Rm[2][1]*Rd10 + Rm[2][2]*Rd20;
        nR[2][1] = Rm[2][0]*Rd01 + Rm[2][1]*Rd11 + Rm[2][2]*Rd21;
        nR[2][2] = Rm[2][0]*Rd02 + Rm[2][1]*Rd12 + Rm[2][2]*Rd22;
        float ntx = Rm[0][0]*tdx + Rm[0][1]*tdy + Rm[0][2]*tdz + tv[0];
        float nty = Rm[1][0]*tdx + Rm[1][1]*tdy + Rm[1][2]*tdz + tv[1];
        float ntz = Rm[2][0]*tdx + Rm[2][1]*tdy + Rm[2][2]*tdz + tv[2];
        #pragma unroll
        for (int i = 0; i < 3; ++i)
            #pragma unroll
            for (int j = 0; j < 3; ++j) Rm[i][j] = nR[i][j];
        tv[0] = ntx; tv[1] = nty; tv[2] = ntz;
    }

    // epilogue: Out = inv(Tsv) * T * Tsv
    {
        float R00 = Rm[0][0], R01 = Rm[0][1], R02 = Rm[0][2];
        float R10 = Rm[1][0], R11 = Rm[1][1], R12 = Rm[1][2];
        float R20 = Rm[2][0], R21 = Rm[2][1], R22 = Rm[2][2];
        float tx = tv[0], ty = tv[1], tz = tv[2];

        float Rv00 = Tsv[0], Rv01 = Tsv[1], Rv02 = Tsv[2],  tvx = Tsv[3];
        float Rv10 = Tsv[4], Rv11 = Tsv[5], Rv12 = Tsv[6],  tvy = Tsv[7];
        float Rv20 = Tsv[8], Rv21 = Tsv[9], Rv22 = Tsv[10], tvz = Tsv[11];

        float P00 = R00*Rv00 + R01*Rv10 + R02*Rv20;
        float P01 = R00*Rv01 + R01*Rv11 + R02*Rv21;
        float P02 = R00*Rv02 + R01*Rv12 + R02*Rv22;
        float P10 = R10*Rv00 + R11*Rv10 + R12*Rv20;
        float P11 = R10*Rv01 + R11*Rv11 + R12*Rv21;
        float P12 = R10*Rv02 + R11*Rv12 + R12*Rv22;
        float P20 = R20*Rv00 + R21*Rv10 + R22*Rv20;
        float P21 = R20*Rv01 + R21*Rv11 + R22*Rv21;
        float P22 = R20*Rv02 + R21*Rv12 + R22*Rv22;
        float Ptx = R00*tvx + R01*tvy + R02*tvz + tx;
        float Pty = R10*tvx + R11*tvy + R12*tvz + ty;
        float Ptz = R20*tvx + R21*tvy + R22*tvz + tz;

        float ex = Ptx - tvx, ey = Pty - tvy, ez = Ptz - tvz;
        float* o = out + (size_t)b * 16;
        o[0]  = Rv00*P00 + Rv10*P10 + Rv20*P20;
        o[1]  = Rv00*P01 + Rv10*P11 + Rv20*P21;
        o[2]  = Rv00*P02 + Rv10*P12 + Rv20*P22;
        o[3]  = Rv00*ex  + Rv10*ey  + Rv20*ez;
        o[4]  = Rv01*P00 + Rv11*P10 + Rv21*P20;
        o[5]  = Rv01*P01 + Rv11*P11 + Rv21*P21;
        o[6]  = Rv01*P02 + Rv11*P12 + Rv21*P22;
        o[7]  = Rv01*ex  + Rv11*ey  + Rv21*ez;
        o[8]  = Rv02*P00 + Rv12*P10 + Rv22*P20;
        o[9]  = Rv02*P01 + Rv12*P11 + Rv22*P21;
        o[10] = Rv02*P02 + Rv12*P12 + Rv22*P22;
        o[11] = Rv02*ex  + Rv12*ey  + Rv22*ez;
        o[12] = 0.0f; o[13] = 0.0f; o[14] = 0.0f; o[15] = 1.0f;
    }
}

extern "C" void kernel_launch(void* const* d_in, const int* in_sizes, int n_in,
                              void* d_out, int out_size, void* d_ws, size_t ws_size,
                              hipStream_t stream)
{
    const float* src4  = (const float*)d_in[0];
    const float* trg4  = (const float*)d_in[1];
    const float* wts   = (const float*)d_in[2];
    const float* Tinit = (const float*)d_in[3];
    const float* icov  = (const float*)d_in[4];
    const float* Tsv   = (const float*)d_in[5];

    const int B = in_sizes[3] / 16;   // T_trg_src_init is (B,4,4)
    float* mom = (float*)d_ws;        // 72*B floats

    hipLaunchKernelGGL(moments_kernel, dim3(B), dim3(BD1), 0, stream,
                       src4, trg4, wts, icov, mom, B);
    hipLaunchKernelGGL(solve_kernel, dim3((B + 63) / 64), dim3(64), 0, stream,
                       mom, Tinit, Tsv, (float*)d_out, B);
}